// Round 1
// baseline (152.975 us; speedup 1.0000x reference)
//
#include <hip/hip_runtime.h>
#include <hip/hip_bf16.h>
#include <stdint.h>

#define N_ROWS 8192
#define DIM    2048
#define OUTD   2048
#define NEXP   8
#define RNK    16
#define ZCOLS  128          // NEXP*RNK
#define KAUG   2176         // DIM + ZCOLS

typedef unsigned short u16;
typedef float  f32x4  __attribute__((ext_vector_type(4)));
typedef __bf16 bf16x8 __attribute__((ext_vector_type(8)));

__device__ __forceinline__ u16 f2bf(float f) {
  unsigned u = __float_as_uint(f);
  return (u16)((u + 0x7fffu + ((u >> 16) & 1u)) >> 16);   // RNE
}

// ---- K1: x -> bf16 into xaug cols [0,DIM) ; fp32 gate logits -> top2 + softmax ----
__global__ __launch_bounds__(256) void k1_convert_gate(
    const float* __restrict__ x, const float* __restrict__ gw,
    const float* __restrict__ gb, u16* __restrict__ xaug,
    int* __restrict__ sel, float* __restrict__ gv)
{
  const int wave = threadIdx.x >> 6;
  const int lane = threadIdx.x & 63;
  const int row0 = blockIdx.x * 8 + wave * 2;   // 2 rows per wave

  float xv[2][32];
  #pragma unroll
  for (int rr = 0; rr < 2; ++rr) {
    const float* xr = x + (size_t)(row0 + rr) * DIM;
    #pragma unroll
    for (int i = 0; i < 8; ++i) {
      float4 v = *(const float4*)(xr + (lane * 4 + i * 256));
      xv[rr][i*4+0] = v.x; xv[rr][i*4+1] = v.y;
      xv[rr][i*4+2] = v.z; xv[rr][i*4+3] = v.w;
    }
  }
  #pragma unroll
  for (int rr = 0; rr < 2; ++rr) {
    u16* dst = xaug + (size_t)(row0 + rr) * KAUG;
    #pragma unroll
    for (int i = 0; i < 8; ++i) {
      ushort4 s;
      s.x = f2bf(xv[rr][i*4+0]); s.y = f2bf(xv[rr][i*4+1]);
      s.z = f2bf(xv[rr][i*4+2]); s.w = f2bf(xv[rr][i*4+3]);
      *(ushort4*)(dst + (lane * 4 + i * 256)) = s;
    }
  }
  float lg[2][NEXP];
  #pragma unroll
  for (int e = 0; e < NEXP; ++e) {
    const float* ge = gw + (size_t)e * DIM;
    float s0 = 0.f, s1 = 0.f;
    #pragma unroll
    for (int i = 0; i < 8; ++i) {
      float4 g4 = *(const float4*)(ge + (lane * 4 + i * 256));
      s0 += xv[0][i*4+0]*g4.x + xv[0][i*4+1]*g4.y + xv[0][i*4+2]*g4.z + xv[0][i*4+3]*g4.w;
      s1 += xv[1][i*4+0]*g4.x + xv[1][i*4+1]*g4.y + xv[1][i*4+2]*g4.z + xv[1][i*4+3]*g4.w;
    }
    #pragma unroll
    for (int off = 32; off > 0; off >>= 1) {
      s0 += __shfl_xor(s0, off);
      s1 += __shfl_xor(s1, off);
    }
    lg[0][e] = s0 + gb[e];
    lg[1][e] = s1 + gb[e];
  }
  if (lane == 0) {
    #pragma unroll
    for (int rr = 0; rr < 2; ++rr) {
      int e0 = 0; float m0 = lg[rr][0];
      #pragma unroll
      for (int e = 1; e < NEXP; ++e) if (lg[rr][e] > m0) { m0 = lg[rr][e]; e0 = e; }
      int e1 = (e0 == 0) ? 1 : 0; float m1 = lg[rr][e1];
      #pragma unroll
      for (int e = 0; e < NEXP; ++e) if (e != e0 && lg[rr][e] > m1) { m1 = lg[rr][e]; e1 = e; }
      float t   = expf(m1 - m0);       // <= 1
      float inv = 1.f / (1.f + t);
      int r = row0 + rr;
      sel[2*r] = e0; sel[2*r+1] = e1;
      gv[2*r]  = inv; gv[2*r+1] = t * inv;
    }
  }
}

// ---- K2: Waug[o] = [bf16(W[o]) | bf16(lora_B[e,o,r])] ; Ab = bf16(lora_A flat) ----
__global__ __launch_bounds__(256) void k2_weights(
    const float* __restrict__ W, const float* __restrict__ lB,
    const float* __restrict__ lA, u16* __restrict__ waug, u16* __restrict__ ab)
{
  const int t = threadIdx.x;
  const int bid = blockIdx.x;
  if (bid < OUTD) {
    const int o = bid;
    const float* wr = W + (size_t)o * DIM;
    u16* dst = waug + (size_t)o * KAUG;
    #pragma unroll
    for (int i = 0; i < 2; ++i) {
      int c = t * 4 + i * 1024;
      float4 v = *(const float4*)(wr + c);
      ushort4 s; s.x = f2bf(v.x); s.y = f2bf(v.y); s.z = f2bf(v.z); s.w = f2bf(v.w);
      *(ushort4*)(dst + c) = s;
    }
    if (t < ZCOLS) {
      int e = t >> 4, r = t & 15;
      dst[DIM + t] = f2bf(lB[((size_t)e * OUTD + o) * RNK + r]);
    }
  } else {
    const int ar = bid - OUTD;          // 0..127 : lora_A flat row
    const float* src = lA + (size_t)ar * DIM;
    u16* dst = ab + (size_t)ar * DIM;
    #pragma unroll
    for (int i = 0; i < 2; ++i) {
      int c = t * 4 + i * 1024;
      float4 v = *(const float4*)(src + c);
      ushort4 s; s.x = f2bf(v.x); s.y = f2bf(v.y); s.z = f2bf(v.z); s.w = f2bf(v.w);
      *(ushort4*)(dst + c) = s;
    }
  }
}

// ---- templated bf16 GEMM, C = A(row-major [M,K]) * B(row-major [N,K])^T ----
// EPI=1: out fp32 += bias   EPI=0: write gated bf16 z into outZ (xaug cols DIM..)
template <int BM, int BN, int BK, int WM, int WN, int MF, int NF, int EPI>
__global__ __launch_bounds__(WM*WN*64) void gemm_bt(
    const u16* __restrict__ A, int lda,
    const u16* __restrict__ Bm, int ldb,
    int Ksz, int grid_n,
    float* __restrict__ outF, int ldo, const float* __restrict__ bias,
    u16* __restrict__ outZ, int ldz,
    const int* __restrict__ sel, const float* __restrict__ gv)
{
  static_assert(BM == WM * MF * 16 && BN == WN * NF * 16 && BK == 64, "geom");
  constexpr int NW   = WM * WN;
  constexpr int ROWB = BK * 2;                    // 128 B per LDS tile row
  __shared__ __align__(16) u16 As[2][BM * BK];
  __shared__ __align__(16) u16 Bs[2][BN * BK];

  const int wave = threadIdx.x >> 6;
  const int lane = threadIdx.x & 63;

  int bid = blockIdx.x;
  const int nwg = gridDim.x;
  if ((nwg & 7) == 0) {                           // bijective XCD swizzle
    const int cpx = nwg >> 3;
    bid = (bid & 7) * cpx + (bid >> 3);
  }
  const int tm = bid / grid_n;
  const int tn = bid % grid_n;
  const size_t row0 = (size_t)tm * BM;
  const size_t col0 = (size_t)tn * BN;

  // linear LDS dest + inverse-swizzled global src; read applies same XOR (rule 21)
  auto stage = [&](const u16* __restrict__ g, int ld, size_t r0, int k0,
                   u16* lds, int nrows) {
    const int nch = nrows * (ROWB / 16);          // 16B chunks, 8 per row
    for (int c0 = wave * 64; c0 < nch; c0 += NW * 64) {
      const int c   = c0 + lane;
      const int r   = c >> 3;
      const int ch  = c & 7;
      const int sch = ch ^ (r & 7);
      const char* src = (const char*)(g + (r0 + (size_t)r) * ld + k0) + (sch << 4);
      __builtin_amdgcn_global_load_lds(
          (__attribute__((address_space(1))) void*)src,
          (__attribute__((address_space(3))) void*)((char*)lds + ((size_t)c0 << 4)),
          16, 0, 0);
    }
  };

  const int wm = wave / WN, wn = wave % WN;
  const int aRow = wm * MF * 16 + (lane & 15);
  const int bRow = wn * NF * 16 + (lane & 15);
  const int kq   = (lane >> 4) << 4;              // byte offset of k-quarter

  f32x4 acc[MF][NF] = {};

  const int nk = Ksz / BK;
  stage(A,  lda, row0, 0, As[0], BM);
  stage(Bm, ldb, col0, 0, Bs[0], BN);
  __syncthreads();

  for (int t = 0; t < nk; ++t) {
    const int cur = t & 1;
    if (t + 1 < nk) {
      stage(A,  lda, row0, (t + 1) * BK, As[cur ^ 1], BM);
      stage(Bm, ldb, col0, (t + 1) * BK, Bs[cur ^ 1], BN);
    }
    const char* ab_ = (const char*)As[cur];
    const char* bb_ = (const char*)Bs[cur];
    #pragma unroll
    for (int ks = 0; ks < BK / 32; ++ks) {
      bf16x8 av[MF], bv[NF];
      #pragma unroll
      for (int mf = 0; mf < MF; ++mf) {
        const int r  = aRow + mf * 16;
        const int bo = (ks * 64 + kq) ^ ((r & 7) << 4);
        av[mf] = *(const bf16x8*)(ab_ + r * ROWB + bo);
      }
      #pragma unroll
      for (int nf = 0; nf < NF; ++nf) {
        const int r  = bRow + nf * 16;
        const int bo = (ks * 64 + kq) ^ ((r & 7) << 4);
        bv[nf] = *(const bf16x8*)(bb_ + r * ROWB + bo);
      }
      #pragma unroll
      for (int mf = 0; mf < MF; ++mf)
        #pragma unroll
        for (int nf = 0; nf < NF; ++nf)
          acc[mf][nf] = __builtin_amdgcn_mfma_f32_16x16x32_bf16(
              av[mf], bv[nf], acc[mf][nf], 0, 0, 0);
    }
    __syncthreads();
  }

  // D layout: col = lane&15, row = (lane>>4)*4 + j   [m89-verified]
  if constexpr (EPI == 1) {
    #pragma unroll
    for (int nf = 0; nf < NF; ++nf) {
      const size_t c = col0 + wn * NF * 16 + nf * 16 + (lane & 15);
      const float bvv = bias[c];
      #pragma unroll
      for (int mf = 0; mf < MF; ++mf) {
        const size_t rb = row0 + wm * MF * 16 + mf * 16 + ((lane >> 4) << 2);
        #pragma unroll
        for (int j = 0; j < 4; ++j)
          outF[(rb + j) * (size_t)ldo + c] = acc[mf][nf][j] + bvv;
      }
    }
  } else {
    #pragma unroll
    for (int mf = 0; mf < MF; ++mf) {
      const size_t rb = row0 + wm * MF * 16 + mf * 16 + ((lane >> 4) << 2);
      #pragma unroll
      for (int j = 0; j < 4; ++j) {
        const size_t rrow = rb + j;
        const int   e0 = sel[2 * rrow],     e1 = sel[2 * rrow + 1];
        const float g0 = gv [2 * rrow],     g1 = gv [2 * rrow + 1];
        #pragma unroll
        for (int nf = 0; nf < NF; ++nf) {
          const int ccol = wn * NF * 16 + nf * 16 + (lane & 15);  // col0 == 0 here
          const int e = ccol >> 4;
          const float s = (e == e0) ? g0 : ((e == e1) ? g1 : 0.f);
          outZ[rrow * (size_t)ldz + ccol] = f2bf(acc[mf][nf][j] * s);
        }
      }
    }
  }
}

extern "C" void kernel_launch(void* const* d_in, const int* in_sizes, int n_in,
                              void* d_out, int out_size, void* d_ws, size_t ws_size,
                              hipStream_t stream) {
  const float* x  = (const float*)d_in[0];
  const float* W  = (const float*)d_in[1];
  const float* b  = (const float*)d_in[2];
  const float* lA = (const float*)d_in[3];
  const float* lB = (const float*)d_in[4];
  const float* gw = (const float*)d_in[5];
  const float* gb = (const float*)d_in[6];
  float* out = (float*)d_out;

  // workspace layout (~43.2 MiB total)
  u16*   xaug = (u16*)d_ws;                          // [8192][2176]
  u16*   waug = xaug + (size_t)N_ROWS * KAUG;        // [2048][2176]
  u16*   ab   = waug + (size_t)OUTD * KAUG;          // [128][2048]
  int*   sel  = (int*)(ab + (size_t)ZCOLS * DIM);    // [8192][2]
  float* gv   = (float*)(sel + 2 * N_ROWS);          // [8192][2]

  // K1: convert x + fp32 gates
  hipLaunchKernelGGL(k1_convert_gate, dim3(N_ROWS / 8), dim3(256), 0, stream,
                     x, gw, gb, xaug, sel, gv);
  // K2: build Waug + Ab
  hipLaunchKernelGGL(k2_weights, dim3(OUTD + ZCOLS), dim3(256), 0, stream,
                     W, lB, lA, waug, ab);
  // K3: xA = xb @ Ab^T  -> gated bf16 z written into xaug cols [DIM, KAUG)
  hipLaunchKernelGGL((gemm_bt<32, 128, 64, 1, 4, 2, 2, 0>),
                     dim3(N_ROWS / 32), dim3(256), 0, stream,
                     xaug, KAUG, ab, DIM, DIM, 1,
                     (float*)nullptr, 0, (const float*)nullptr,
                     xaug + DIM, KAUG, sel, gv);
  // K4: out = xaug @ Waug^T + b
  hipLaunchKernelGGL((gemm_bt<128, 128, 64, 2, 2, 4, 4, 1>),
                     dim3((N_ROWS / 128) * (OUTD / 128)), dim3(256), 0, stream,
                     xaug, KAUG, waug, KAUG, KAUG, OUTD / 128,
                     out, OUTD, b,
                     (u16*)nullptr, 0, (const int*)nullptr, (const float*)nullptr);
}

// Round 2
// 141.653 us; speedup vs baseline: 1.0799x; 1.0799x over previous
//
#include <hip/hip_runtime.h>
#include <hip/hip_bf16.h>
#include <stdint.h>

#define N_ROWS 8192
#define DIM    2048
#define OUTD   2048
#define NEXP   8
#define RNK    16
#define ZCOLS  128          // NEXP*RNK
#define KAUG   2176         // DIM + ZCOLS

typedef unsigned short u16;
typedef float  f32x4  __attribute__((ext_vector_type(4)));
typedef __bf16 bf16x8 __attribute__((ext_vector_type(8)));

__device__ __forceinline__ u16 f2bf(float f) {
  unsigned u = __float_as_uint(f);
  return (u16)((u + 0x7fffu + ((u >> 16) & 1u)) >> 16);   // RNE
}

// ---- K1: x -> bf16 into xaug cols [0,DIM) ; fp32 gate logits -> top2 + softmax ----
__global__ __launch_bounds__(256) void k1_convert_gate(
    const float* __restrict__ x, const float* __restrict__ gw,
    const float* __restrict__ gb, u16* __restrict__ xaug,
    int* __restrict__ sel, float* __restrict__ gv)
{
  const int wave = threadIdx.x >> 6;
  const int lane = threadIdx.x & 63;
  const int row0 = blockIdx.x * 8 + wave * 2;   // 2 rows per wave

  float xv[2][32];
  #pragma unroll
  for (int rr = 0; rr < 2; ++rr) {
    const float* xr = x + (size_t)(row0 + rr) * DIM;
    #pragma unroll
    for (int i = 0; i < 8; ++i) {
      float4 v = *(const float4*)(xr + (lane * 4 + i * 256));
      xv[rr][i*4+0] = v.x; xv[rr][i*4+1] = v.y;
      xv[rr][i*4+2] = v.z; xv[rr][i*4+3] = v.w;
    }
  }
  #pragma unroll
  for (int rr = 0; rr < 2; ++rr) {
    u16* dst = xaug + (size_t)(row0 + rr) * KAUG;
    #pragma unroll
    for (int i = 0; i < 8; ++i) {
      ushort4 s;
      s.x = f2bf(xv[rr][i*4+0]); s.y = f2bf(xv[rr][i*4+1]);
      s.z = f2bf(xv[rr][i*4+2]); s.w = f2bf(xv[rr][i*4+3]);
      *(ushort4*)(dst + (lane * 4 + i * 256)) = s;
    }
  }
  float lg[2][NEXP];
  #pragma unroll
  for (int e = 0; e < NEXP; ++e) {
    const float* ge = gw + (size_t)e * DIM;
    float s0 = 0.f, s1 = 0.f;
    #pragma unroll
    for (int i = 0; i < 8; ++i) {
      float4 g4 = *(const float4*)(ge + (lane * 4 + i * 256));
      s0 += xv[0][i*4+0]*g4.x + xv[0][i*4+1]*g4.y + xv[0][i*4+2]*g4.z + xv[0][i*4+3]*g4.w;
      s1 += xv[1][i*4+0]*g4.x + xv[1][i*4+1]*g4.y + xv[1][i*4+2]*g4.z + xv[1][i*4+3]*g4.w;
    }
    #pragma unroll
    for (int off = 32; off > 0; off >>= 1) {
      s0 += __shfl_xor(s0, off);
      s1 += __shfl_xor(s1, off);
    }
    lg[0][e] = s0 + gb[e];
    lg[1][e] = s1 + gb[e];
  }
  if (lane == 0) {
    #pragma unroll
    for (int rr = 0; rr < 2; ++rr) {
      int e0 = 0; float m0 = lg[rr][0];
      #pragma unroll
      for (int e = 1; e < NEXP; ++e) if (lg[rr][e] > m0) { m0 = lg[rr][e]; e0 = e; }
      int e1 = (e0 == 0) ? 1 : 0; float m1 = lg[rr][e1];
      #pragma unroll
      for (int e = 0; e < NEXP; ++e) if (e != e0 && lg[rr][e] > m1) { m1 = lg[rr][e]; e1 = e; }
      float t   = expf(m1 - m0);       // <= 1
      float inv = 1.f / (1.f + t);
      int r = row0 + rr;
      sel[2*r] = e0; sel[2*r+1] = e1;
      gv[2*r]  = inv; gv[2*r+1] = t * inv;
    }
  }
}

// ---- K2: Waug[o] = [bf16(W[o]) | bf16(lora_B[e,o,r])] ; Ab = bf16(lora_A flat) ----
__global__ __launch_bounds__(256) void k2_weights(
    const float* __restrict__ W, const float* __restrict__ lB,
    const float* __restrict__ lA, u16* __restrict__ waug, u16* __restrict__ ab)
{
  const int t = threadIdx.x;
  const int bid = blockIdx.x;
  if (bid < OUTD) {
    const int o = bid;
    const float* wr = W + (size_t)o * DIM;
    u16* dst = waug + (size_t)o * KAUG;
    #pragma unroll
    for (int i = 0; i < 2; ++i) {
      int c = t * 4 + i * 1024;
      float4 v = *(const float4*)(wr + c);
      ushort4 s; s.x = f2bf(v.x); s.y = f2bf(v.y); s.z = f2bf(v.z); s.w = f2bf(v.w);
      *(ushort4*)(dst + c) = s;
    }
    if (t < ZCOLS) {
      int e = t >> 4, r = t & 15;
      dst[DIM + t] = f2bf(lB[((size_t)e * OUTD + o) * RNK + r]);
    }
  } else {
    const int ar = bid - OUTD;          // 0..127 : lora_A flat row
    const float* src = lA + (size_t)ar * DIM;
    u16* dst = ab + (size_t)ar * DIM;
    #pragma unroll
    for (int i = 0; i < 2; ++i) {
      int c = t * 4 + i * 1024;
      float4 v = *(const float4*)(src + c);
      ushort4 s; s.x = f2bf(v.x); s.y = f2bf(v.y); s.z = f2bf(v.z); s.w = f2bf(v.w);
      *(ushort4*)(dst + c) = s;
    }
  }
}

// ---- K3 GEMM (small, unchanged): C = A[M,K] * B[N,K]^T, EPI=0 gated-z epilogue ----
template <int BM, int BN, int BK, int WM, int WN, int MF, int NF, int EPI>
__global__ __launch_bounds__(WM*WN*64) void gemm_bt(
    const u16* __restrict__ A, int lda,
    const u16* __restrict__ Bm, int ldb,
    int Ksz, int grid_n,
    float* __restrict__ outF, int ldo, const float* __restrict__ bias,
    u16* __restrict__ outZ, int ldz,
    const int* __restrict__ sel, const float* __restrict__ gv)
{
  static_assert(BM == WM * MF * 16 && BN == WN * NF * 16 && BK == 64, "geom");
  constexpr int NW   = WM * WN;
  constexpr int ROWB = BK * 2;                    // 128 B per LDS tile row
  __shared__ __align__(16) u16 As[2][BM * BK];
  __shared__ __align__(16) u16 Bs[2][BN * BK];

  const int wave = threadIdx.x >> 6;
  const int lane = threadIdx.x & 63;

  int bid = blockIdx.x;
  const int nwg = gridDim.x;
  if ((nwg & 7) == 0) {
    const int cpx = nwg >> 3;
    bid = (bid & 7) * cpx + (bid >> 3);
  }
  const int tm = bid / grid_n;
  const int tn = bid % grid_n;
  const size_t row0 = (size_t)tm * BM;
  const size_t col0 = (size_t)tn * BN;

  auto stage = [&](const u16* __restrict__ g, int ld, size_t r0, int k0,
                   u16* lds, int nrows) {
    const int nch = nrows * (ROWB / 16);
    for (int c0 = wave * 64; c0 < nch; c0 += NW * 64) {
      const int c   = c0 + lane;
      const int r   = c >> 3;
      const int ch  = c & 7;
      const int sch = ch ^ (r & 7);
      const char* src = (const char*)(g + (r0 + (size_t)r) * ld + k0) + (sch << 4);
      __builtin_amdgcn_global_load_lds(
          (__attribute__((address_space(1))) void*)src,
          (__attribute__((address_space(3))) void*)((char*)lds + ((size_t)c0 << 4)),
          16, 0, 0);
    }
  };

  const int wm = wave / WN, wn = wave % WN;
  const int aRow = wm * MF * 16 + (lane & 15);
  const int bRow = wn * NF * 16 + (lane & 15);
  const int kq   = (lane >> 4) << 4;

  f32x4 acc[MF][NF] = {};

  const int nk = Ksz / BK;
  stage(A,  lda, row0, 0, As[0], BM);
  stage(Bm, ldb, col0, 0, Bs[0], BN);
  __syncthreads();

  for (int t = 0; t < nk; ++t) {
    const int cur = t & 1;
    if (t + 1 < nk) {
      stage(A,  lda, row0, (t + 1) * BK, As[cur ^ 1], BM);
      stage(Bm, ldb, col0, (t + 1) * BK, Bs[cur ^ 1], BN);
    }
    const char* ab_ = (const char*)As[cur];
    const char* bb_ = (const char*)Bs[cur];
    #pragma unroll
    for (int ks = 0; ks < BK / 32; ++ks) {
      bf16x8 av[MF], bv[NF];
      #pragma unroll
      for (int mf = 0; mf < MF; ++mf) {
        const int r  = aRow + mf * 16;
        const int bo = (ks * 64 + kq) ^ ((r & 7) << 4);
        av[mf] = *(const bf16x8*)(ab_ + r * ROWB + bo);
      }
      #pragma unroll
      for (int nf = 0; nf < NF; ++nf) {
        const int r  = bRow + nf * 16;
        const int bo = (ks * 64 + kq) ^ ((r & 7) << 4);
        bv[nf] = *(const bf16x8*)(bb_ + r * ROWB + bo);
      }
      #pragma unroll
      for (int mf = 0; mf < MF; ++mf)
        #pragma unroll
        for (int nf = 0; nf < NF; ++nf)
          acc[mf][nf] = __builtin_amdgcn_mfma_f32_16x16x32_bf16(
              av[mf], bv[nf], acc[mf][nf], 0, 0, 0);
    }
    __syncthreads();
  }

  if constexpr (EPI == 1) {
    #pragma unroll
    for (int nf = 0; nf < NF; ++nf) {
      const size_t c = col0 + wn * NF * 16 + nf * 16 + (lane & 15);
      const float bvv = bias[c];
      #pragma unroll
      for (int mf = 0; mf < MF; ++mf) {
        const size_t rb = row0 + wm * MF * 16 + mf * 16 + ((lane >> 4) << 2);
        #pragma unroll
        for (int j = 0; j < 4; ++j)
          outF[(rb + j) * (size_t)ldo + c] = acc[mf][nf][j] + bvv;
      }
    }
  } else {
    #pragma unroll
    for (int mf = 0; mf < MF; ++mf) {
      const size_t rb = row0 + wm * MF * 16 + mf * 16 + ((lane >> 4) << 2);
      #pragma unroll
      for (int j = 0; j < 4; ++j) {
        const size_t rrow = rb + j;
        const int   e0 = sel[2 * rrow],     e1 = sel[2 * rrow + 1];
        const float g0 = gv [2 * rrow],     g1 = gv [2 * rrow + 1];
        #pragma unroll
        for (int nf = 0; nf < NF; ++nf) {
          const int ccol = wn * NF * 16 + nf * 16 + (lane & 15);
          const int e = ccol >> 4;
          const float s = (e == e0) ? g0 : ((e == e1) ? g1 : 0.f);
          outZ[rrow * (size_t)ldz + ccol] = f2bf(acc[mf][nf][j] * s);
        }
      }
    }
  }
}

// ---- K4: 256x256 tile, BK=32, 4-slot LDS ring, counted vmcnt, 1 barrier/K-step ----
// 8 waves (2M x 4N), per-wave 128x64 output, MF=8, NF=4.
// LDS: A slots 4 x 16KB at [0,64K), B slots 4 x 16KB at [64K,128K).
// Slot layout: 256 rows x 4 chunks(16B); chunk swizzle sch = ch ^ (row&3)
// (linear LDS dest + inverse-swizzled global source; ds_read applies same XOR).
__global__ __launch_bounds__(512, 2) void gemm256_pipe(
    const u16* __restrict__ A, int lda,
    const u16* __restrict__ Bm, int ldb,
    int Ksz, int grid_n,
    float* __restrict__ outF, int ldo, const float* __restrict__ bias)
{
  __shared__ __align__(16) u16 smem[65536];      // 128 KiB

  const int tid  = threadIdx.x;
  const int wave = tid >> 6;
  const int lane = tid & 63;

  int bid = blockIdx.x;
  const int nwg = gridDim.x;
  if ((nwg & 7) == 0) {                          // bijective XCD swizzle
    const int cpx = nwg >> 3;
    bid = (bid & 7) * cpx + (bid >> 3);
  }
  const int tm = bid / grid_n;
  const int tn = bid % grid_n;
  const size_t row0 = (size_t)tm * 256;
  const size_t col0 = (size_t)tn * 256;

  // ---- staging addresses: 1024 chunks per matrix per slot, 2 per thread ----
  const int rc  = tid >> 2;                       // chunk row (0..127); +128 for 2nd
  const int sch = (tid & 3) ^ (rc & 3);           // swizzled source chunk
  const char* aS0 = (const char*)(A  + (row0 + (size_t)rc)         * lda) + (sch << 4);
  const char* aS1 = (const char*)(A  + (row0 + (size_t)(rc + 128)) * lda) + (sch << 4);
  const char* bS0 = (const char*)(Bm + (col0 + (size_t)rc)         * ldb) + (sch << 4);
  const char* bS1 = (const char*)(Bm + (col0 + (size_t)(rc + 128)) * ldb) + (sch << 4);
  char* ldsA = (char*)smem + wave * 1024;         // wave-uniform dest (+ lane*16 by HW)
  char* ldsB = (char*)smem + 65536 + wave * 1024;

  auto stage = [&](int tt) {
    const size_t ko = (size_t)tt << 6;            // k-step byte advance (32 elem * 2B)
    const int    sb = (tt & 3) << 14;             // slot byte offset
    __builtin_amdgcn_global_load_lds(
        (__attribute__((address_space(1))) void*)(aS0 + ko),
        (__attribute__((address_space(3))) void*)(ldsA + sb), 16, 0, 0);
    __builtin_amdgcn_global_load_lds(
        (__attribute__((address_space(1))) void*)(aS1 + ko),
        (__attribute__((address_space(3))) void*)(ldsA + sb + 8192), 16, 0, 0);
    __builtin_amdgcn_global_load_lds(
        (__attribute__((address_space(1))) void*)(bS0 + ko),
        (__attribute__((address_space(3))) void*)(ldsB + sb), 16, 0, 0);
    __builtin_amdgcn_global_load_lds(
        (__attribute__((address_space(1))) void*)(bS1 + ko),
        (__attribute__((address_space(3))) void*)(ldsB + sb + 8192), 16, 0, 0);
  };

  // ---- fragment read offsets (same XOR family as staging) ----
  const int wm = wave >> 2, wn = wave & 3;
  const int swzk = ((lane >> 4) ^ (lane & 3)) << 4;
  const int offA = (wm * 128 + (lane & 15)) * 64 + swzk;
  const int offB = (wn * 64  + (lane & 15)) * 64 + swzk;

  f32x4 acc[8][4] = {};

  const int nk = Ksz / 32;                        // 68
  stage(0); stage(1); stage(2);

  for (int t = 0; t < nk; ++t) {
    // slot t must be landed; slots t+1,t+2 may stay in flight (8 loads)
    if      (t + 2 < nk) asm volatile("s_waitcnt vmcnt(8)" ::: "memory");
    else if (t + 1 < nk) asm volatile("s_waitcnt vmcnt(4)" ::: "memory");
    else                 asm volatile("s_waitcnt vmcnt(0)" ::: "memory");
    __builtin_amdgcn_s_barrier();
    __builtin_amdgcn_sched_barrier(0);

    if (t + 3 < nk) stage(t + 3);                 // overwrites slot consumed at t-1

    const char* sa = (const char*)smem + ((t & 3) << 14);
    const char* sb = (const char*)smem + 65536 + ((t & 3) << 14);

    bf16x8 av[8], bv[4];
    #pragma unroll
    for (int mf = 0; mf < 8; ++mf)
      av[mf] = *(const bf16x8*)(sa + offA + mf * 1024);
    #pragma unroll
    for (int nf = 0; nf < 4; ++nf)
      bv[nf] = *(const bf16x8*)(sb + offB + nf * 1024);

    __builtin_amdgcn_s_setprio(1);
    #pragma unroll
    for (int mf = 0; mf < 8; ++mf)
      #pragma unroll
      for (int nf = 0; nf < 4; ++nf)
        acc[mf][nf] = __builtin_amdgcn_mfma_f32_16x16x32_bf16(
            av[mf], bv[nf], acc[mf][nf], 0, 0, 0);
    __builtin_amdgcn_s_setprio(0);
  }

  // epilogue: D layout col = lane&15, row = (lane>>4)*4 + j
  #pragma unroll
  for (int nf = 0; nf < 4; ++nf) {
    const size_t c = col0 + wn * 64 + nf * 16 + (lane & 15);
    const float bvv = bias[c];
    #pragma unroll
    for (int mf = 0; mf < 8; ++mf) {
      const size_t rb = row0 + wm * 128 + mf * 16 + ((lane >> 4) << 2);
      #pragma unroll
      for (int j = 0; j < 4; ++j)
        outF[(rb + j) * (size_t)ldo + c] = acc[mf][nf][j] + bvv;
    }
  }
}

extern "C" void kernel_launch(void* const* d_in, const int* in_sizes, int n_in,
                              void* d_out, int out_size, void* d_ws, size_t ws_size,
                              hipStream_t stream) {
  const float* x  = (const float*)d_in[0];
  const float* W  = (const float*)d_in[1];
  const float* b  = (const float*)d_in[2];
  const float* lA = (const float*)d_in[3];
  const float* lB = (const float*)d_in[4];
  const float* gw = (const float*)d_in[5];
  const float* gb = (const float*)d_in[6];
  float* out = (float*)d_out;

  u16*   xaug = (u16*)d_ws;                          // [8192][2176]
  u16*   waug = xaug + (size_t)N_ROWS * KAUG;        // [2048][2176]
  u16*   ab   = waug + (size_t)OUTD * KAUG;          // [128][2048]
  int*   sel  = (int*)(ab + (size_t)ZCOLS * DIM);    // [8192][2]
  float* gv   = (float*)(sel + 2 * N_ROWS);          // [8192][2]

  hipLaunchKernelGGL(k1_convert_gate, dim3(N_ROWS / 8), dim3(256), 0, stream,
                     x, gw, gb, xaug, sel, gv);
  hipLaunchKernelGGL(k2_weights, dim3(OUTD + ZCOLS), dim3(256), 0, stream,
                     W, lB, lA, waug, ab);
  hipLaunchKernelGGL((gemm_bt<32, 128, 64, 1, 4, 2, 2, 0>),
                     dim3(N_ROWS / 32), dim3(256), 0, stream,
                     xaug, KAUG, ab, DIM, DIM, 1,
                     (float*)nullptr, 0, (const float*)nullptr,
                     xaug + DIM, KAUG, sel, gv);
  hipLaunchKernelGGL(gemm256_pipe,
                     dim3((N_ROWS / 256) * (OUTD / 256)), dim3(512), 0, stream,
                     xaug, KAUG, waug, KAUG, KAUG, OUTD / 256,
                     out, OUTD, b);
}

// Round 3
// 126.286 us; speedup vs baseline: 1.2113x; 1.1217x over previous
//
#include <hip/hip_runtime.h>
#include <hip/hip_bf16.h>
#include <stdint.h>

#define N_ROWS 8192
#define DIM    2048
#define OUTD   2048
#define NEXP   8
#define RNK    16
#define ZCOLS  128          // NEXP*RNK
#define KAUG   2176         // DIM + ZCOLS
#define KSPLIT 4
#define KSLICE (DIM / KSPLIT)   // 512

typedef unsigned short u16;
typedef float  f32x4  __attribute__((ext_vector_type(4)));
typedef __bf16 bf16x8 __attribute__((ext_vector_type(8)));

__device__ __forceinline__ u16 f2bf(float f) {
  unsigned u = __float_as_uint(f);
  return (u16)((u + 0x7fffu + ((u >> 16) & 1u)) >> 16);   // RNE
}

// ---- K1: x -> bf16 into xaug cols [0,DIM) ; fp32 gate logits -> top2 + softmax ----
__global__ __launch_bounds__(256) void k1_convert_gate(
    const float* __restrict__ x, const float* __restrict__ gw,
    const float* __restrict__ gb, u16* __restrict__ xaug,
    int* __restrict__ sel, float* __restrict__ gv)
{
  const int wave = threadIdx.x >> 6;
  const int lane = threadIdx.x & 63;
  const int row0 = blockIdx.x * 8 + wave * 2;   // 2 rows per wave

  float xv[2][32];
  #pragma unroll
  for (int rr = 0; rr < 2; ++rr) {
    const float* xr = x + (size_t)(row0 + rr) * DIM;
    #pragma unroll
    for (int i = 0; i < 8; ++i) {
      float4 v = *(const float4*)(xr + (lane * 4 + i * 256));
      xv[rr][i*4+0] = v.x; xv[rr][i*4+1] = v.y;
      xv[rr][i*4+2] = v.z; xv[rr][i*4+3] = v.w;
    }
  }
  #pragma unroll
  for (int rr = 0; rr < 2; ++rr) {
    u16* dst = xaug + (size_t)(row0 + rr) * KAUG;
    #pragma unroll
    for (int i = 0; i < 8; ++i) {
      ushort4 s;
      s.x = f2bf(xv[rr][i*4+0]); s.y = f2bf(xv[rr][i*4+1]);
      s.z = f2bf(xv[rr][i*4+2]); s.w = f2bf(xv[rr][i*4+3]);
      *(ushort4*)(dst + (lane * 4 + i * 256)) = s;
    }
  }
  float lg[2][NEXP];
  #pragma unroll
  for (int e = 0; e < NEXP; ++e) {
    const float* ge = gw + (size_t)e * DIM;
    float s0 = 0.f, s1 = 0.f;
    #pragma unroll
    for (int i = 0; i < 8; ++i) {
      float4 g4 = *(const float4*)(ge + (lane * 4 + i * 256));
      s0 += xv[0][i*4+0]*g4.x + xv[0][i*4+1]*g4.y + xv[0][i*4+2]*g4.z + xv[0][i*4+3]*g4.w;
      s1 += xv[1][i*4+0]*g4.x + xv[1][i*4+1]*g4.y + xv[1][i*4+2]*g4.z + xv[1][i*4+3]*g4.w;
    }
    #pragma unroll
    for (int off = 32; off > 0; off >>= 1) {
      s0 += __shfl_xor(s0, off);
      s1 += __shfl_xor(s1, off);
    }
    lg[0][e] = s0 + gb[e];
    lg[1][e] = s1 + gb[e];
  }
  if (lane == 0) {
    #pragma unroll
    for (int rr = 0; rr < 2; ++rr) {
      int e0 = 0; float m0 = lg[rr][0];
      #pragma unroll
      for (int e = 1; e < NEXP; ++e) if (lg[rr][e] > m0) { m0 = lg[rr][e]; e0 = e; }
      int e1 = (e0 == 0) ? 1 : 0; float m1 = lg[rr][e1];
      #pragma unroll
      for (int e = 0; e < NEXP; ++e) if (e != e0 && lg[rr][e] > m1) { m1 = lg[rr][e]; e1 = e; }
      float t   = expf(m1 - m0);       // <= 1
      float inv = 1.f / (1.f + t);
      int r = row0 + rr;
      sel[2*r] = e0; sel[2*r+1] = e1;
      gv[2*r]  = inv; gv[2*r+1] = t * inv;
    }
  }
}

// ---- K2: Waug[o] = [bf16(W[o]) | bf16(lora_B[e,o,r])] ; Ab = bf16(lora_A flat) ----
__global__ __launch_bounds__(256) void k2_weights(
    const float* __restrict__ W, const float* __restrict__ lB,
    const float* __restrict__ lA, u16* __restrict__ waug, u16* __restrict__ ab)
{
  const int t = threadIdx.x;
  const int bid = blockIdx.x;
  if (bid < OUTD) {
    const int o = bid;
    const float* wr = W + (size_t)o * DIM;
    u16* dst = waug + (size_t)o * KAUG;
    #pragma unroll
    for (int i = 0; i < 2; ++i) {
      int c = t * 4 + i * 1024;
      float4 v = *(const float4*)(wr + c);
      ushort4 s; s.x = f2bf(v.x); s.y = f2bf(v.y); s.z = f2bf(v.z); s.w = f2bf(v.w);
      *(ushort4*)(dst + c) = s;
    }
    if (t < ZCOLS) {
      int e = t >> 4, r = t & 15;
      dst[DIM + t] = f2bf(lB[((size_t)e * OUTD + o) * RNK + r]);
    }
  } else {
    const int ar = bid - OUTD;          // 0..127 : lora_A flat row
    const float* src = lA + (size_t)ar * DIM;
    u16* dst = ab + (size_t)ar * DIM;
    #pragma unroll
    for (int i = 0; i < 2; ++i) {
      int c = t * 4 + i * 1024;
      float4 v = *(const float4*)(src + c);
      ushort4 s; s.x = f2bf(v.x); s.y = f2bf(v.y); s.z = f2bf(v.z); s.w = f2bf(v.w);
      *(ushort4*)(dst + c) = s;
    }
  }
}

// ---- K3: split-K GEMM  zpart[ksl] = xb[:, ksl*512:(ksl+1)*512] @ ab_slice^T ----
// 128x128 tile, BK=64, 4 waves (2x2), MF=NF=4, fp32 partial output (no gating).
template <int BM, int BN, int BK, int WM, int WN, int MF, int NF>
__global__ __launch_bounds__(WM*WN*64) void gemm_ksplit(
    const u16* __restrict__ A, int lda,
    const u16* __restrict__ Bm, int ldb,
    int Ksz, int gm, float* __restrict__ outP)
{
  static_assert(BM == WM * MF * 16 && BN == WN * NF * 16 && BK == 64, "geom");
  constexpr int NW   = WM * WN;
  constexpr int ROWB = BK * 2;                    // 128 B rows
  __shared__ __align__(16) u16 As[2][BM * BK];
  __shared__ __align__(16) u16 Bs[2][BN * BK];

  const int wave = threadIdx.x >> 6;
  const int lane = threadIdx.x & 63;

  int bid = blockIdx.x;
  const int nwg = gridDim.x;
  if ((nwg & 7) == 0) {
    const int cpx = nwg >> 3;
    bid = (bid & 7) * cpx + (bid >> 3);
  }
  const int tm  = bid % gm;
  const int ksl = bid / gm;
  const size_t row0 = (size_t)tm * BM;
  const u16* Ak = A  + (size_t)ksl * Ksz;         // column offset within row
  const u16* Bk = Bm + (size_t)ksl * Ksz;

  auto stage = [&](const u16* __restrict__ g, int ld, size_t r0, int k0,
                   u16* lds, int nrows) {
    const int nch = nrows * (ROWB / 16);
    for (int c0 = wave * 64; c0 < nch; c0 += NW * 64) {
      const int c   = c0 + lane;
      const int r   = c >> 3;
      const int ch  = c & 7;
      const int sch = ch ^ (r & 7);
      const char* src = (const char*)(g + (r0 + (size_t)r) * ld + k0) + (sch << 4);
      __builtin_amdgcn_global_load_lds(
          (__attribute__((address_space(1))) void*)src,
          (__attribute__((address_space(3))) void*)((char*)lds + ((size_t)c0 << 4)),
          16, 0, 0);
    }
  };

  const int wm = wave / WN, wn = wave % WN;
  const int aRow = wm * MF * 16 + (lane & 15);
  const int bRow = wn * NF * 16 + (lane & 15);
  const int kq   = (lane >> 4) << 4;

  f32x4 acc[MF][NF] = {};

  const int nk = Ksz / BK;                        // 8
  stage(Ak, lda, row0, 0, As[0], BM);
  stage(Bk, ldb, 0,    0, Bs[0], BN);
  __syncthreads();

  for (int t = 0; t < nk; ++t) {
    const int cur = t & 1;
    if (t + 1 < nk) {
      stage(Ak, lda, row0, (t + 1) * BK, As[cur ^ 1], BM);
      stage(Bk, ldb, 0,    (t + 1) * BK, Bs[cur ^ 1], BN);
    }
    const char* ab_ = (const char*)As[cur];
    const char* bb_ = (const char*)Bs[cur];
    #pragma unroll
    for (int ks = 0; ks < BK / 32; ++ks) {
      bf16x8 av[MF], bv[NF];
      #pragma unroll
      for (int mf = 0; mf < MF; ++mf) {
        const int r  = aRow + mf * 16;
        const int bo = (ks * 64 + kq) ^ ((r & 7) << 4);
        av[mf] = *(const bf16x8*)(ab_ + r * ROWB + bo);
      }
      #pragma unroll
      for (int nf = 0; nf < NF; ++nf) {
        const int r  = bRow + nf * 16;
        const int bo = (ks * 64 + kq) ^ ((r & 7) << 4);
        bv[nf] = *(const bf16x8*)(bb_ + r * ROWB + bo);
      }
      #pragma unroll
      for (int mf = 0; mf < MF; ++mf)
        #pragma unroll
        for (int nf = 0; nf < NF; ++nf)
          acc[mf][nf] = __builtin_amdgcn_mfma_f32_16x16x32_bf16(
              av[mf], bv[nf], acc[mf][nf], 0, 0, 0);
    }
    __syncthreads();
  }

  float* op = outP + (size_t)ksl * N_ROWS * ZCOLS;
  #pragma unroll
  for (int nf = 0; nf < NF; ++nf) {
    const int c = wn * NF * 16 + nf * 16 + (lane & 15);
    #pragma unroll
    for (int mf = 0; mf < MF; ++mf) {
      const size_t rb = row0 + wm * MF * 16 + mf * 16 + ((lane >> 4) << 2);
      #pragma unroll
      for (int j = 0; j < 4; ++j)
        op[(rb + j) * ZCOLS + c] = acc[mf][nf][j];
    }
  }
}

// ---- K3b: z = gate(sum_k zpart[k]) -> bf16 into xaug cols [DIM, KAUG) ----
__global__ __launch_bounds__(256) void k3b_reduce_gate(
    const float* __restrict__ zpart, const int* __restrict__ sel,
    const float* __restrict__ gv, u16* __restrict__ xaug)
{
  const int idx = blockIdx.x * 256 + threadIdx.x;   // N_ROWS*32 threads
  const int row = idx >> 5;
  const int c4  = (idx & 31) << 2;                  // 4 cols, same expert block
  const float* zr = zpart + (size_t)row * ZCOLS + c4;
  const size_t sl = (size_t)N_ROWS * ZCOLS;
  float4 s = *(const float4*)zr;
  #pragma unroll
  for (int k = 1; k < KSPLIT; ++k) {
    float4 v = *(const float4*)(zr + k * sl);
    s.x += v.x; s.y += v.y; s.z += v.z; s.w += v.w;
  }
  const int e  = c4 >> 4;
  const int e0 = sel[2 * row], e1 = sel[2 * row + 1];
  const float g = (e == e0) ? gv[2 * row] : ((e == e1) ? gv[2 * row + 1] : 0.f);
  ushort4 o;
  o.x = f2bf(s.x * g); o.y = f2bf(s.y * g);
  o.z = f2bf(s.z * g); o.w = f2bf(s.w * g);
  *(ushort4*)(xaug + (size_t)row * KAUG + DIM + c4) = o;
}

// ---- K4: 256x256 tile, BK=64 (128B rows, ch^(r&7) swizzle -> 0 conflicts),
// 2-slot LDS ring (128 KiB), counted vmcnt(8), 2 barriers / K-tile,
// 8 waves (2M x 4N), per-wave 128x64, MF=8 NF=4, 2 sub-phases per K-tile. ----
__global__ __launch_bounds__(512, 2) void gemm256_pipe(
    const u16* __restrict__ A, int lda,
    const u16* __restrict__ Bm, int ldb,
    int Ksz, int grid_n,
    float* __restrict__ outF, int ldo, const float* __restrict__ bias)
{
  __shared__ __align__(16) u16 smem[65536];      // 128 KiB: A[2][32K] | B[2][32K]

  const int tid  = threadIdx.x;
  const int wave = tid >> 6;
  const int lane = tid & 63;

  int bid = blockIdx.x;
  const int nwg = gridDim.x;
  if ((nwg & 7) == 0) {                          // bijective XCD swizzle
    const int cpx = nwg >> 3;
    bid = (bid & 7) * cpx + (bid >> 3);
  }
  const int tm = bid / grid_n;
  const int tn = bid % grid_n;
  const size_t row0 = (size_t)tm * 256;
  const size_t col0 = (size_t)tn * 256;

  // staging: per thread 4 A-chunks + 4 B-chunks per K-tile.
  // load i covers chunks [wave*64 + i*512 .. +64): row = wave*8+i*64+(lane>>3),
  // lds chunk pos = lane&7 holds global chunk (lane&7)^(r&7); r&7 = (lane>>3)&7.
  const int l3  = lane >> 3;
  const int sch = ((lane & 7) ^ l3) << 4;
  const char* aSrc = (const char*)(A  + (row0 + (size_t)(wave * 8 + l3)) * lda) + sch;
  const char* bSrc = (const char*)(Bm + (col0 + (size_t)(wave * 8 + l3)) * ldb) + sch;
  const size_t arst = (size_t)lda * 128;         // 64 rows stride in bytes
  const size_t brst = (size_t)ldb * 128;
  char* ldsA = (char*)smem + wave * 1024;        // + lane*16 by HW
  char* ldsB = (char*)smem + 65536 + wave * 1024;

  auto stage = [&](int tt) {
    const size_t ko = (size_t)tt * 128;          // K-tile byte advance (64 elem)
    const int    sb = (tt & 1) << 15;            // slot offset (32 KiB)
    #pragma unroll
    for (int i = 0; i < 4; ++i)
      __builtin_amdgcn_global_load_lds(
          (__attribute__((address_space(1))) void*)(aSrc + ko + i * arst),
          (__attribute__((address_space(3))) void*)(ldsA + sb + i * 8192), 16, 0, 0);
    #pragma unroll
    for (int i = 0; i < 4; ++i)
      __builtin_amdgcn_global_load_lds(
          (__attribute__((address_space(1))) void*)(bSrc + ko + i * brst),
          (__attribute__((address_space(3))) void*)(ldsB + sb + i * 8192), 16, 0, 0);
  };

  // fragment reads: row r byte base r*128; chunk kc = ks*4+(lane>>4), pos kc^(r&7)
  const int wm = wave >> 2, wn = wave & 3;
  const int x0 = ((lane >> 4) ^ (lane & 7)) << 4;   // ks=0 xor term; ks=1 is ^64
  const int offA0 = wm * 16384 + (lane & 15) * 128 + x0;
  const int offB0 = wn * 8192  + (lane & 15) * 128 + x0;

  f32x4 acc[8][4] = {};

  const int nk = Ksz / 64;                        // 34
  stage(0); stage(1);

  for (int t = 0; t < nk; ++t) {
    if (t + 1 < nk) asm volatile("s_waitcnt vmcnt(8)" ::: "memory");
    else            asm volatile("s_waitcnt vmcnt(0)" ::: "memory");
    __builtin_amdgcn_s_barrier();
    __builtin_amdgcn_sched_barrier(0);

    const char* sa = (const char*)smem + ((t & 1) << 15);
    const char* sb = (const char*)smem + 65536 + ((t & 1) << 15);

    bf16x8 av[8], bv[4];
    // ---- sub-phase ks=0 ----
    #pragma unroll
    for (int mf = 0; mf < 8; ++mf) av[mf] = *(const bf16x8*)(sa + offA0 + mf * 2048);
    #pragma unroll
    for (int nf = 0; nf < 4; ++nf) bv[nf] = *(const bf16x8*)(sb + offB0 + nf * 2048);
    __builtin_amdgcn_s_setprio(1);
    #pragma unroll
    for (int mf = 0; mf < 8; ++mf)
      #pragma unroll
      for (int nf = 0; nf < 4; ++nf)
        acc[mf][nf] = __builtin_amdgcn_mfma_f32_16x16x32_bf16(
            av[mf], bv[nf], acc[mf][nf], 0, 0, 0);
    __builtin_amdgcn_s_setprio(0);

    // ---- sub-phase ks=1: read frags, then free the slot and prefetch ----
    #pragma unroll
    for (int mf = 0; mf < 8; ++mf) av[mf] = *(const bf16x8*)(sa + (offA0 ^ 64) + mf * 2048);
    #pragma unroll
    for (int nf = 0; nf < 4; ++nf) bv[nf] = *(const bf16x8*)(sb + (offB0 ^ 64) + nf * 2048);
    asm volatile("s_waitcnt lgkmcnt(0)" ::: "memory");
    __builtin_amdgcn_s_barrier();                 // all waves done reading slot t&1
    __builtin_amdgcn_sched_barrier(0);
    if (t + 2 < nk) stage(t + 2);                 // overwrites slot t&1 (now free)
    __builtin_amdgcn_s_setprio(1);
    #pragma unroll
    for (int mf = 0; mf < 8; ++mf)
      #pragma unroll
      for (int nf = 0; nf < 4; ++nf)
        acc[mf][nf] = __builtin_amdgcn_mfma_f32_16x16x32_bf16(
            av[mf], bv[nf], acc[mf][nf], 0, 0, 0);
    __builtin_amdgcn_s_setprio(0);
  }

  // epilogue: D layout col = lane&15, row = (lane>>4)*4 + j
  #pragma unroll
  for (int nf = 0; nf < 4; ++nf) {
    const size_t c = col0 + wn * 64 + nf * 16 + (lane & 15);
    const float bvv = bias[c];
    #pragma unroll
    for (int mf = 0; mf < 8; ++mf) {
      const size_t rb = row0 + wm * 128 + mf * 16 + ((lane >> 4) << 2);
      #pragma unroll
      for (int j = 0; j < 4; ++j)
        outF[(rb + j) * (size_t)ldo + c] = acc[mf][nf][j] + bvv;
    }
  }
}

extern "C" void kernel_launch(void* const* d_in, const int* in_sizes, int n_in,
                              void* d_out, int out_size, void* d_ws, size_t ws_size,
                              hipStream_t stream) {
  const float* x  = (const float*)d_in[0];
  const float* W  = (const float*)d_in[1];
  const float* b  = (const float*)d_in[2];
  const float* lA = (const float*)d_in[3];
  const float* lB = (const float*)d_in[4];
  const float* gw = (const float*)d_in[5];
  const float* gb = (const float*)d_in[6];
  float* out = (float*)d_out;

  // workspace layout (~62 MiB)
  u16*   xaug  = (u16*)d_ws;                          // [8192][2176]
  u16*   waug  = xaug + (size_t)N_ROWS * KAUG;        // [2048][2176]
  u16*   ab    = waug + (size_t)OUTD * KAUG;          // [128][2048]
  int*   sel   = (int*)(ab + (size_t)ZCOLS * DIM);    // [8192][2]
  float* gv    = (float*)(sel + 2 * N_ROWS);          // [8192][2]
  float* zpart = (float*)(gv + 2 * N_ROWS);           // [4][8192][128] fp32

  hipLaunchKernelGGL(k1_convert_gate, dim3(N_ROWS / 8), dim3(256), 0, stream,
                     x, gw, gb, xaug, sel, gv);
  hipLaunchKernelGGL(k2_weights, dim3(OUTD + ZCOLS), dim3(256), 0, stream,
                     W, lB, lA, waug, ab);
  hipLaunchKernelGGL((gemm_ksplit<128, 128, 64, 2, 2, 4, 4>),
                     dim3((N_ROWS / 128) * KSPLIT), dim3(256), 0, stream,
                     xaug, KAUG, ab, DIM, KSLICE, N_ROWS / 128, zpart);
  hipLaunchKernelGGL(k3b_reduce_gate, dim3(N_ROWS * 32 / 256), dim3(256), 0, stream,
                     zpart, sel, gv, xaug);
  hipLaunchKernelGGL(gemm256_pipe,
                     dim3((N_ROWS / 256) * (OUTD / 256)), dim3(512), 0, stream,
                     xaug, KAUG, waug, KAUG, KAUG, OUTD / 256,
                     out, OUTD, b);
}

// Round 4
// 120.680 us; speedup vs baseline: 1.2676x; 1.0465x over previous
//
#include <hip/hip_runtime.h>
#include <hip/hip_bf16.h>
#include <stdint.h>

#define N_ROWS 8192
#define DIM    2048
#define OUTD   2048
#define NEXP   8
#define RNK    16
#define ZCOLS  128          // NEXP*RNK
#define KAUG   2176         // DIM + ZCOLS

typedef unsigned short u16;
typedef float  f32x4  __attribute__((ext_vector_type(4)));
typedef __bf16 bf16x8 __attribute__((ext_vector_type(8)));

__device__ __forceinline__ u16 f2bf(float f) {
  unsigned u = __float_as_uint(f);
  return (u16)((u + 0x7fffu + ((u >> 16) & 1u)) >> 16);   // RNE
}

// ---- K2: Waug[o] = [bf16(W[o]) | bf16(lora_B[e,o,r])] ; Ab = bf16(lora_A flat) ----
__global__ __launch_bounds__(256) void k2_weights(
    const float* __restrict__ W, const float* __restrict__ lB,
    const float* __restrict__ lA, u16* __restrict__ waug, u16* __restrict__ ab)
{
  const int t = threadIdx.x;
  const int bid = blockIdx.x;
  if (bid < OUTD) {
    const int o = bid;
    const float* wr = W + (size_t)o * DIM;
    u16* dst = waug + (size_t)o * KAUG;
    #pragma unroll
    for (int i = 0; i < 2; ++i) {
      int c = t * 4 + i * 1024;
      float4 v = *(const float4*)(wr + c);
      ushort4 s; s.x = f2bf(v.x); s.y = f2bf(v.y); s.z = f2bf(v.z); s.w = f2bf(v.w);
      *(ushort4*)(dst + c) = s;
    }
    if (t < ZCOLS) {
      int e = t >> 4, r = t & 15;
      dst[DIM + t] = f2bf(lB[((size_t)e * OUTD + o) * RNK + r]);
    }
  } else {
    const int ar = bid - OUTD;          // 0..127 : lora_A flat row
    const float* src = lA + (size_t)ar * DIM;
    u16* dst = ab + (size_t)ar * DIM;
    #pragma unroll
    for (int i = 0; i < 2; ++i) {
      int c = t * 4 + i * 1024;
      float4 v = *(const float4*)(src + c);
      ushort4 s; s.x = f2bf(v.x); s.y = f2bf(v.y); s.z = f2bf(v.z); s.w = f2bf(v.w);
      *(ushort4*)(dst + c) = s;
    }
  }
}

// ---- KF: fused x->bf16 convert + fp32 gates + xA MFMA + gated z write ----
// 512 blocks x 256 thr (4 waves); block owns 16 rows; 32 chunks of 64 cols.
// thread t: row r = t>>4, col-quad q = t&15 (4 cols). Gates stay fp32 exact.
__global__ __launch_bounds__(256) void kf_fused(
    const float* __restrict__ x, const float* __restrict__ gw,
    const float* __restrict__ gb, const u16* __restrict__ ab,
    u16* __restrict__ xaug)
{
  __shared__ __align__(16) u16 la[8192];     // [128][64] bf16, swizzled (16 KB)
  __shared__ __align__(16) u16 xb[1024];     // [16][64]  bf16, swizzled (2 KB)
  __shared__ float4 gates[16];               // per-row {g0,g1,e0,e1}

  const int t    = threadIdx.x;
  const int wave = t >> 6;
  const int lane = t & 63;
  const int r    = t >> 4;                   // 0..15
  const int q    = t & 15;                   // col quad
  const size_t row0 = (size_t)blockIdx.x * 16;

  // la staging addresses (global_load_lds, linear dest + inv-swizzled source)
  int   lrow[4], lsch[4];
  #pragma unroll
  for (int i = 0; i < 4; ++i) {
    const int g = t + i * 256;               // chunk id 0..1023
    lrow[i] = g >> 3;
    lsch[i] = (g & 7) ^ (lrow[i] & 7);
  }

  float4 xv, gwv[8];
  xv = *(const float4*)(x + (row0 + r) * DIM + q * 4);
  #pragma unroll
  for (int e = 0; e < NEXP; ++e)
    gwv[e] = *(const float4*)(gw + (size_t)e * DIM + q * 4);

  float ga[NEXP] = {};
  f32x4 acc[2] = {};
  const int nfA = 2 * wave, nfB = 2 * wave + 1;

  for (int c = 0; c < 32; ++c) {
    const int C0 = c * 64;
    // stage la chunk (16 KB via global_load_lds)
    #pragma unroll
    for (int i = 0; i < 4; ++i) {
      const char* src = (const char*)(ab + (size_t)lrow[i] * DIM + C0 + lsch[i] * 8);
      __builtin_amdgcn_global_load_lds(
          (__attribute__((address_space(1))) void*)src,
          (__attribute__((address_space(3))) void*)((char*)la + (wave * 64 + i * 256) * 16),
          16, 0, 0);
    }
    __builtin_amdgcn_sched_barrier(0);
    // prefetch next chunk's x + gw
    float4 xvn, gwvn[8];
    if (c + 1 < 32) {
      xvn = *(const float4*)(x + (row0 + r) * DIM + C0 + 64 + q * 4);
      #pragma unroll
      for (int e = 0; e < NEXP; ++e)
        gwvn[e] = *(const float4*)(gw + (size_t)e * DIM + C0 + 64 + q * 4);
    }
    __builtin_amdgcn_sched_barrier(0);
    // compute with current xv
    ushort4 s; s.x = f2bf(xv.x); s.y = f2bf(xv.y); s.z = f2bf(xv.z); s.w = f2bf(xv.w);
    *(ushort4*)(xaug + (row0 + r) * KAUG + C0 + q * 4) = s;
    #pragma unroll
    for (int e = 0; e < NEXP; ++e)
      ga[e] += xv.x * gwv[e].x + xv.y * gwv[e].y + xv.z * gwv[e].z + xv.w * gwv[e].w;
    {
      const int ch = q >> 1;
      const int by = r * 128 + ((ch ^ (r & 7)) * 16) + (q & 1) * 8;
      *(ushort4*)((char*)xb + by) = s;
    }
    if (c + 1 < 32) asm volatile("s_waitcnt vmcnt(9)" ::: "memory");
    else            asm volatile("s_waitcnt vmcnt(0)" ::: "memory");
    asm volatile("s_waitcnt lgkmcnt(0)" ::: "memory");
    __builtin_amdgcn_s_barrier();

    // MFMA: xb[16x64] x la[128x64]^T -> acc 16x128 (wave covers 32 cols)
    #pragma unroll
    for (int ks = 0; ks < 2; ++ks) {
      const int ra  = lane & 15;
      const int pa  = ((ks * 4 + (lane >> 4)) ^ (ra & 7)) * 16;
      bf16x8 avf = *(const bf16x8*)((char*)xb + ra * 128 + pa);
      const int rbA = (lane & 15) + 16 * nfA;
      const int rbB = (lane & 15) + 16 * nfB;
      bf16x8 bvA = *(const bf16x8*)((char*)la + rbA * 128 + (((ks * 4 + (lane >> 4)) ^ (rbA & 7)) * 16));
      bf16x8 bvB = *(const bf16x8*)((char*)la + rbB * 128 + (((ks * 4 + (lane >> 4)) ^ (rbB & 7)) * 16));
      acc[0] = __builtin_amdgcn_mfma_f32_16x16x32_bf16(avf, bvA, acc[0], 0, 0, 0);
      acc[1] = __builtin_amdgcn_mfma_f32_16x16x32_bf16(avf, bvB, acc[1], 0, 0, 0);
    }
    __builtin_amdgcn_s_barrier();
    xv = xvn;
    #pragma unroll
    for (int e = 0; e < NEXP; ++e) gwv[e] = gwvn[e];
  }

  // gate reduce over the 16 threads sharing a row, then top-2 softmax (fp32)
  #pragma unroll
  for (int e = 0; e < NEXP; ++e) {
    float v = ga[e];
    v += __shfl_xor(v, 1); v += __shfl_xor(v, 2);
    v += __shfl_xor(v, 4); v += __shfl_xor(v, 8);
    ga[e] = v + gb[e];
  }
  if (q == 0) {
    int e0 = 0; float m0 = ga[0];
    #pragma unroll
    for (int e = 1; e < NEXP; ++e) if (ga[e] > m0) { m0 = ga[e]; e0 = e; }
    int e1 = (e0 == 0) ? 1 : 0; float m1 = ga[e1];
    #pragma unroll
    for (int e = 0; e < NEXP; ++e) if (e != e0 && ga[e] > m1) { m1 = ga[e]; e1 = e; }
    float tt  = expf(m1 - m0);
    float inv = 1.f / (1.f + tt);
    float4 gg; gg.x = inv; gg.y = tt * inv;
    gg.z = __int_as_float(e0); gg.w = __int_as_float(e1);
    gates[r] = gg;
  }
  __syncthreads();

  // gated z write: frag nfl covers expert e = 2*wave+nfl exactly
  #pragma unroll
  for (int nfl = 0; nfl < 2; ++nfl) {
    const int e = 2 * wave + nfl;
    const int n = e * 16 + (lane & 15);
    #pragma unroll
    for (int j = 0; j < 4; ++j) {
      const int m = (lane >> 4) * 4 + j;
      float4 gg = gates[m];
      const float g = (e == __float_as_int(gg.z)) ? gg.x
                    : ((e == __float_as_int(gg.w)) ? gg.y : 0.f);
      xaug[(row0 + m) * KAUG + DIM + n] = f2bf(acc[nfl][j] * g);
    }
  }
}

// ---- K4: 256x256 tile, BK=64, 2-slot ring, counted vmcnt(8), 3-group MFMA interleave ----
__global__ __launch_bounds__(512, 2) void gemm256_pipe(
    const u16* __restrict__ A, int lda,
    const u16* __restrict__ Bm, int ldb,
    int Ksz, int grid_n,
    float* __restrict__ outF, int ldo, const float* __restrict__ bias)
{
  __shared__ __align__(16) u16 smem[65536];      // 128 KiB: A[2][32K] | B[2][32K]

  const int tid  = threadIdx.x;
  const int wave = tid >> 6;
  const int lane = tid & 63;

  int bid = blockIdx.x;
  const int nwg = gridDim.x;
  if ((nwg & 7) == 0) {                          // bijective XCD swizzle
    const int cpx = nwg >> 3;
    bid = (bid & 7) * cpx + (bid >> 3);
  }
  const int tm = bid / grid_n;
  const int tn = bid % grid_n;
  const size_t row0 = (size_t)tm * 256;
  const size_t col0 = (size_t)tn * 256;

  const int l3  = lane >> 3;
  const int sch = ((lane & 7) ^ l3) << 4;
  const char* aSrc = (const char*)(A  + (row0 + (size_t)(wave * 8 + l3)) * lda) + sch;
  const char* bSrc = (const char*)(Bm + (col0 + (size_t)(wave * 8 + l3)) * ldb) + sch;
  const size_t arst = (size_t)lda * 128;
  const size_t brst = (size_t)ldb * 128;
  char* ldsA = (char*)smem + wave * 1024;
  char* ldsB = (char*)smem + 65536 + wave * 1024;

  auto stage = [&](int tt) {
    const size_t ko = (size_t)tt * 128;
    const int    sb = (tt & 1) << 15;
    #pragma unroll
    for (int i = 0; i < 4; ++i)
      __builtin_amdgcn_global_load_lds(
          (__attribute__((address_space(1))) void*)(aSrc + ko + i * arst),
          (__attribute__((address_space(3))) void*)(ldsA + sb + i * 8192), 16, 0, 0);
    #pragma unroll
    for (int i = 0; i < 4; ++i)
      __builtin_amdgcn_global_load_lds(
          (__attribute__((address_space(1))) void*)(bSrc + ko + i * brst),
          (__attribute__((address_space(3))) void*)(ldsB + sb + i * 8192), 16, 0, 0);
  };

  const int wm = wave >> 2, wn = wave & 3;
  const int x0 = ((lane >> 4) ^ (lane & 7)) << 4;
  const int offA0 = wm * 16384 + (lane & 15) * 128 + x0;
  const int offB0 = wn * 8192  + (lane & 15) * 128 + x0;

  f32x4 acc[8][4] = {};

  const int nk = Ksz / 64;                        // 34
  stage(0); stage(1);

  for (int t = 0; t < nk; ++t) {
    if (t + 1 < nk) asm volatile("s_waitcnt vmcnt(8)" ::: "memory");
    else            asm volatile("s_waitcnt vmcnt(0)" ::: "memory");
    __builtin_amdgcn_s_barrier();
    __builtin_amdgcn_sched_barrier(0);

    const char* sa = (const char*)smem + ((t & 1) << 15);
    const char* sb = (const char*)smem + 65536 + ((t & 1) << 15);

    bf16x8 av0[8], bv0[4], av1[8], bv1[4];
    // ks0 reads
    #pragma unroll
    for (int mf = 0; mf < 8; ++mf) av0[mf] = *(const bf16x8*)(sa + offA0 + mf * 2048);
    #pragma unroll
    for (int nf = 0; nf < 4; ++nf) bv0[nf] = *(const bf16x8*)(sb + offB0 + nf * 2048);
    // group 1: ks0 x nf0-1 (16 MFMA) — overlaps ks0 read returns
    __builtin_amdgcn_s_setprio(1);
    #pragma unroll
    for (int mf = 0; mf < 8; ++mf)
      #pragma unroll
      for (int nf = 0; nf < 2; ++nf)
        acc[mf][nf] = __builtin_amdgcn_mfma_f32_16x16x32_bf16(
            av0[mf], bv0[nf], acc[mf][nf], 0, 0, 0);
    __builtin_amdgcn_s_setprio(0);
    // ks1 reads — issue overlaps group-2 MFMA
    #pragma unroll
    for (int mf = 0; mf < 8; ++mf) av1[mf] = *(const bf16x8*)(sa + (offA0 ^ 64) + mf * 2048);
    #pragma unroll
    for (int nf = 0; nf < 4; ++nf) bv1[nf] = *(const bf16x8*)(sb + (offB0 ^ 64) + nf * 2048);
    // group 2: ks0 x nf2-3 (16 MFMA)
    __builtin_amdgcn_s_setprio(1);
    #pragma unroll
    for (int mf = 0; mf < 8; ++mf)
      #pragma unroll
      for (int nf = 2; nf < 4; ++nf)
        acc[mf][nf] = __builtin_amdgcn_mfma_f32_16x16x32_bf16(
            av0[mf], bv0[nf], acc[mf][nf], 0, 0, 0);
    __builtin_amdgcn_s_setprio(0);
    // slot free after all reads complete in every wave
    asm volatile("s_waitcnt lgkmcnt(0)" ::: "memory");
    __builtin_amdgcn_s_barrier();
    __builtin_amdgcn_sched_barrier(0);
    if (t + 2 < nk) stage(t + 2);
    // group 3: ks1 x all nf (32 MFMA) — covers staging
    __builtin_amdgcn_s_setprio(1);
    #pragma unroll
    for (int mf = 0; mf < 8; ++mf)
      #pragma unroll
      for (int nf = 0; nf < 4; ++nf)
        acc[mf][nf] = __builtin_amdgcn_mfma_f32_16x16x32_bf16(
            av1[mf], bv1[nf], acc[mf][nf], 0, 0, 0);
    __builtin_amdgcn_s_setprio(0);
  }

  #pragma unroll
  for (int nf = 0; nf < 4; ++nf) {
    const size_t c = col0 + wn * 64 + nf * 16 + (lane & 15);
    const float bvv = bias[c];
    #pragma unroll
    for (int mf = 0; mf < 8; ++mf) {
      const size_t rb = row0 + wm * 128 + mf * 16 + ((lane >> 4) << 2);
      #pragma unroll
      for (int j = 0; j < 4; ++j)
        outF[(rb + j) * (size_t)ldo + c] = acc[mf][nf][j] + bvv;
    }
  }
}

extern "C" void kernel_launch(void* const* d_in, const int* in_sizes, int n_in,
                              void* d_out, int out_size, void* d_ws, size_t ws_size,
                              hipStream_t stream) {
  const float* x  = (const float*)d_in[0];
  const float* W  = (const float*)d_in[1];
  const float* b  = (const float*)d_in[2];
  const float* lA = (const float*)d_in[3];
  const float* lB = (const float*)d_in[4];
  const float* gw = (const float*)d_in[5];
  const float* gb = (const float*)d_in[6];
  float* out = (float*)d_out;

  // workspace (~45 MiB)
  u16* xaug = (u16*)d_ws;                          // [8192][2176]
  u16* waug = xaug + (size_t)N_ROWS * KAUG;        // [2048][2176]
  u16* ab   = waug + (size_t)OUTD * KAUG;          // [128][2048]

  hipLaunchKernelGGL(k2_weights, dim3(OUTD + ZCOLS), dim3(256), 0, stream,
                     W, lB, lA, waug, ab);
  hipLaunchKernelGGL(kf_fused, dim3(N_ROWS / 16), dim3(256), 0, stream,
                     x, gw, gb, ab, xaug);
  hipLaunchKernelGGL(gemm256_pipe,
                     dim3((N_ROWS / 256) * (OUTD / 256)), dim3(512), 0, stream,
                     xaug, KAUG, waug, KAUG, KAUG, OUTD / 256,
                     out, OUTD, b);
}